// Round 2
// baseline (3629.708 us; speedup 1.0000x reference)
//
#include <hip/hip_runtime.h>
#include <hip/hip_bf16.h>

// ---- problem constants (fixed by setup_inputs) ----
#define NN   32768
#define EE   262144
#define SS   128
#define NF_  90
#define NC_  36
#define OD_  64
#define D0_  190
#define DX_  380
#define GIN_ 256
#define GH_  512

// ---------------------------------------------------------------------------
// degree / CSR build
// ---------------------------------------------------------------------------
__global__ void deg_count(const int* __restrict__ dst, int* __restrict__ deg) {
  int e = blockIdx.x * 256 + threadIdx.x;
  if (e < EE) atomicAdd(&deg[dst[e]], 1);
}

__global__ __launch_bounds__(1024) void scan_kernel(const int* __restrict__ deg,
                                                    int* __restrict__ offsets) {
  __shared__ int buf[1024];
  __shared__ int carry_s;
  int tid = threadIdx.x;
  if (tid == 0) carry_s = 0;
  __syncthreads();
  for (int chunk = 0; chunk < NN / 1024; ++chunk) {
    int i = chunk * 1024 + tid;
    int v = deg[i];
    buf[tid] = v;
    __syncthreads();
    for (int d = 1; d < 1024; d <<= 1) {
      int t = (tid >= d) ? buf[tid - d] : 0;
      __syncthreads();
      if (tid >= d) buf[tid] += t;
      __syncthreads();
    }
    int incl = buf[tid];
    int carry = carry_s;
    offsets[i] = carry + incl - v;   // exclusive
    __syncthreads();
    if (tid == 1023) carry_s = carry + incl;
    __syncthreads();
  }
  if (tid == 0) offsets[NN] = carry_s;
}

__global__ void inv_deg_k(const int* __restrict__ deg, float* __restrict__ inv_deg) {
  int n = blockIdx.x * 256 + threadIdx.x;
  if (n < NN) inv_deg[n] = 1.0f / fmaxf((float)deg[n], 1.0f);
}

__global__ void bucket_k(const int* __restrict__ src, const int* __restrict__ dst,
                         const int* __restrict__ offsets, int* __restrict__ cursor,
                         int* __restrict__ srcs) {
  int e = blockIdx.x * 256 + threadIdx.x;
  if (e < EE) {
    int d = dst[e];
    int pos = offsets[d] + atomicAdd(&cursor[d], 1);
    srcs[pos] = src[e];
  }
}

// ---------------------------------------------------------------------------
// x0 = concat([node_features, node_config_features, emb_table[node_ops]])
// ---------------------------------------------------------------------------
__global__ void build_x0(const float* __restrict__ nf, const float* __restrict__ ncf,
                         const float* __restrict__ emb, const int* __restrict__ ops,
                         float* __restrict__ x0) {
  int idx = blockIdx.x * 256 + threadIdx.x;
  if (idx >= NN * D0_) return;
  int n = idx / D0_;
  int c = idx - n * D0_;
  float v;
  if (c < NF_)            v = nf[n * NF_ + c];
  else if (c < NF_ + NC_) v = ncf[n * NC_ + (c - NF_)];
  else                    v = emb[ops[n] * OD_ + (c - (NF_ + NC_))];
  x0[idx] = v;
}

// ---------------------------------------------------------------------------
// Two-phase GEMM (NT): C = act(A1*B1^T + A2*B2^T + bias), row-major, guarded.
// 64x64 tile, BK=16, 256 threads, 4x4 per-thread microtile.
// Phase 2 skipped when K2 == 0.
// ---------------------------------------------------------------------------
__device__ __forceinline__ void gemm_phase(
    const float* __restrict__ A, int lda,
    const float* __restrict__ B, int ldb, int K,
    int M, int Nout, int block_m, int block_n,
    int a_r, int a_c, int tm, int tn,
    float (&acc)[4][4], float (*As)[64], float (*Bs)[64])
{
  for (int k0 = 0; k0 < K; k0 += 16) {
#pragma unroll
    for (int i = 0; i < 4; ++i) {
      int gm = block_m + a_r;
      int gk = k0 + a_c + i;
      As[a_c + i][a_r] = (gm < M && gk < K) ? A[(long)gm * lda + gk] : 0.0f;
    }
#pragma unroll
    for (int i = 0; i < 4; ++i) {
      int gn = block_n + a_r;
      int gk = k0 + a_c + i;
      Bs[a_c + i][a_r] = (gn < Nout && gk < K) ? B[(long)gn * ldb + gk] : 0.0f;
    }
    __syncthreads();
#pragma unroll
    for (int k = 0; k < 16; ++k) {
      float av[4], bv[4];
#pragma unroll
      for (int i = 0; i < 4; ++i) av[i] = As[k][tm + i];
#pragma unroll
      for (int j = 0; j < 4; ++j) bv[j] = Bs[k][tn + j];
#pragma unroll
      for (int i = 0; i < 4; ++i)
#pragma unroll
        for (int j = 0; j < 4; ++j)
          acc[i][j] += av[i] * bv[j];
    }
    __syncthreads();
  }
}

__global__ __launch_bounds__(256) void gemm2(
    const float* __restrict__ A1, int lda1,
    const float* __restrict__ B1, int ldb1, int K1,
    const float* __restrict__ A2, int lda2,
    const float* __restrict__ B2, int ldb2, int K2,
    const float* __restrict__ bias,
    float* __restrict__ C, int ldc,
    int M, int Nout, int act)
{
  __shared__ float As[16][64];
  __shared__ float Bs[16][64];
  int tid = threadIdx.x;
  int block_m = blockIdx.y * 64;
  int block_n = blockIdx.x * 64;
  int tm = (tid >> 4) * 4;
  int tn = (tid & 15) * 4;
  int a_r = tid >> 2;          // 0..63
  int a_c = (tid & 3) * 4;     // 0,4,8,12
  float acc[4][4] = {};
  gemm_phase(A1, lda1, B1, ldb1, K1, M, Nout, block_m, block_n,
             a_r, a_c, tm, tn, acc, As, Bs);
  if (K2 > 0)
    gemm_phase(A2, lda2, B2, ldb2, K2, M, Nout, block_m, block_n,
               a_r, a_c, tm, tn, acc, As, Bs);
#pragma unroll
  for (int i = 0; i < 4; ++i) {
    int gm = block_m + tm + i;
    if (gm >= M) continue;
#pragma unroll
    for (int j = 0; j < 4; ++j) {
      int gn = block_n + tn + j;
      if (gn >= Nout) continue;
      float v = acc[i][j] + bias[gn];
      if (act == 1) v = (v >= 0.0f) ? v : 0.01f * v;
      C[(long)gm * ldc + gn] = v;
    }
  }
}

// ---------------------------------------------------------------------------
// Graph-wise LayerNorm: per-segment (256 rows x D feats) mean/var, per-feature affine
// ---------------------------------------------------------------------------
__global__ __launch_bounds__(256) void gln_stats(const float* __restrict__ x, int ld, int D,
                                                 float* __restrict__ seg_mean,
                                                 float* __restrict__ seg_inv) {
  int s = blockIdx.x;
  const float* base = x + (long)s * 256 * ld;
  float sum = 0.0f, ssq = 0.0f;
  for (int r = 0; r < 256; ++r) {
    const float* row = base + (long)r * ld;
    for (int c = threadIdx.x; c < D; c += 256) {
      float v = row[c];
      sum += v;
      ssq += v * v;
    }
  }
  __shared__ float s1[256], s2[256];
  int tid = threadIdx.x;
  s1[tid] = sum; s2[tid] = ssq;
  __syncthreads();
  for (int off = 128; off > 0; off >>= 1) {
    if (tid < off) { s1[tid] += s1[tid + off]; s2[tid] += s2[tid + off]; }
    __syncthreads();
  }
  if (tid == 0) {
    float cnt = 256.0f * (float)D;
    float m = s1[0] / cnt;
    float var = s2[0] / cnt - m * m;
    seg_mean[s] = m;
    seg_inv[s] = rsqrtf(var + 1e-5f);
  }
}

__global__ __launch_bounds__(256) void gln_apply(float* __restrict__ x, int ld, int D,
                                                 const float* __restrict__ seg_mean,
                                                 const float* __restrict__ seg_inv,
                                                 const float* __restrict__ g,
                                                 const float* __restrict__ be) {
  int r = blockIdx.x;
  int s = r >> 8;
  float m = seg_mean[s];
  float inv = seg_inv[s];
  float* row = x + (long)r * ld;
  for (int c = threadIdx.x; c < D; c += 256) {
    row[c] = (row[c] - m) * inv * g[c] + be[c];
  }
}

// ---------------------------------------------------------------------------
// neighbor-mean aggregation via CSR gather
// ---------------------------------------------------------------------------
__global__ void aggregate_k(const float* __restrict__ x, int ldx,
                            float* __restrict__ agg, int lda, int D,
                            const int* __restrict__ offsets,
                            const int* __restrict__ srcs,
                            const float* __restrict__ inv_deg) {
  int n = blockIdx.x;
  int start = offsets[n], end = offsets[n + 1];
  float w = inv_deg[n];
  for (int f = threadIdx.x; f < D; f += blockDim.x) {
    float acc = 0.0f;
    for (int e = start; e < end; ++e) {
      acc += x[(long)srcs[e] * ldx + f];
    }
    agg[(long)n * lda + f] = acc * w;
  }
}

// ---------------------------------------------------------------------------
// PairNorm: column sums -> mean + inv-denominator -> apply in place (+ReLU)
// ---------------------------------------------------------------------------
__global__ __launch_bounds__(512) void pn_stats(const float* __restrict__ y,
                                                float* __restrict__ colsum,
                                                float* __restrict__ colssq) {
  int f = threadIdx.x;
  int r0 = blockIdx.x * 256;
  float s = 0.0f, ss = 0.0f;
  for (int r = 0; r < 256; ++r) {
    float v = y[(long)(r0 + r) * GH_ + f];
    s += v;
    ss += v * v;
  }
  atomicAdd(&colsum[f], s);
  atomicAdd(&colssq[f], ss);
}

__global__ __launch_bounds__(512) void pn_finalize(const float* __restrict__ colsum,
                                                   const float* __restrict__ colssq,
                                                   float* __restrict__ mu,
                                                   float* __restrict__ invd) {
  int f = threadIdx.x;
  float m = colsum[f] / (float)NN;
  mu[f] = m;
  float t = colssq[f] / (float)NN - m * m;
  __shared__ float buf[512];
  buf[f] = t;
  __syncthreads();
  for (int off = 256; off > 0; off >>= 1) {
    if (f < off) buf[f] += buf[f + off];
    __syncthreads();
  }
  if (f == 0) invd[0] = 1.0f / (1e-5f + sqrtf(fmaxf(buf[0], 0.0f)));
}

__global__ __launch_bounds__(512) void pn_apply(float* __restrict__ y,
                                                const float* __restrict__ mu,
                                                const float* __restrict__ invd,
                                                int do_relu) {
  int r = blockIdx.x;
  int f = threadIdx.x;
  long idx = (long)r * GH_ + f;
  float v = (y[idx] - mu[f]) * invd[0];
  if (do_relu) v = fmaxf(v, 0.0f);
  y[idx] = v;
}

// ---------------------------------------------------------------------------
// final pooling + head: out[s] = sum_f (sum_r y3[s*256+r, f]) * wc[f] + bc
// ---------------------------------------------------------------------------
__global__ __launch_bounds__(512) void pool_out(const float* __restrict__ y3,
                                                const float* __restrict__ wc,
                                                const float* __restrict__ bc,
                                                float* __restrict__ out) {
  int s = blockIdx.x;
  int f = threadIdx.x;
  const float* base = y3 + (long)s * 256 * GH_;
  float acc = 0.0f;
  for (int r = 0; r < 256; ++r) acc += base[(long)r * GH_ + f];
  acc *= wc[f];
  __shared__ float buf[512];
  buf[f] = acc;
  __syncthreads();
  for (int off = 256; off > 0; off >>= 1) {
    if (f < off) buf[f] += buf[f + off];
    __syncthreads();
  }
  if (f == 0) out[s] = buf[0] + bc[0];
}

// ---------------------------------------------------------------------------
extern "C" void kernel_launch(void* const* d_in, const int* in_sizes, int n_in,
                              void* d_out, int out_size, void* d_ws, size_t ws_size,
                              hipStream_t stream) {
  const float* node_features = (const float*)d_in[0];
  const float* node_config   = (const float*)d_in[1];
  const float* emb_table     = (const float*)d_in[2];
  const float* w1  = (const float*)d_in[3];
  const float* b1  = (const float*)d_in[4];
  const float* g1  = (const float*)d_in[5];
  const float* be1 = (const float*)d_in[6];
  const float* w2  = (const float*)d_in[7];
  const float* b2  = (const float*)d_in[8];
  const float* g2  = (const float*)d_in[9];
  const float* be2 = (const float*)d_in[10];
  const float* wl1 = (const float*)d_in[11];
  const float* bl1 = (const float*)d_in[12];
  const float* wr1 = (const float*)d_in[13];
  const float* wl2 = (const float*)d_in[14];
  const float* bl2 = (const float*)d_in[15];
  const float* wr2 = (const float*)d_in[16];
  const float* wl3 = (const float*)d_in[17];
  const float* bl3 = (const float*)d_in[18];
  const float* wr3 = (const float*)d_in[19];
  const float* wc  = (const float*)d_in[20];
  const float* bc  = (const float*)d_in[21];
  const int* node_ops = (const int*)d_in[22];
  const int* edges    = (const int*)d_in[23];
  float* out = (float*)d_out;

  char* ws = (char*)d_ws;
  size_t off = 0;
  auto alloc = [&](size_t bytes) -> void* {
    void* p = ws + off;
    off += (bytes + 255) & ~(size_t)255;
    return p;
  };

  int*   deg_i   = (int*)alloc(NN * 4);
  int*   cursor  = (int*)alloc(NN * 4);
  int*   offsets = (int*)alloc((NN + 1) * 4);
  int*   srcs    = (int*)alloc(EE * 4);
  float* inv_deg = (float*)alloc(NN * 4);
  float* seg_mean= (float*)alloc(SS * 4);
  float* seg_inv = (float*)alloc(SS * 4);
  float* colsum  = (float*)alloc(512 * 4);   // 2048B; colssq directly follows
  float* colssq  = (float*)alloc(512 * 4);
  float* mu      = (float*)alloc(512 * 4);
  float* invd    = (float*)alloc(256);
  // three rotating [N,512] fp32 slabs (64 MB each; 192 MB total)
  float* bufA    = (float*)alloc((size_t)NN * 512 * 4);
  float* bufB    = (float*)alloc((size_t)NN * 512 * 4);
  float* bufC    = (float*)alloc((size_t)NN * 512 * 4);

  const int* esrc = edges;
  const int* edst = edges + EE;

  // ---- CSR build ----
  hipMemsetAsync(deg_i, 0, NN * 4, stream);
  hipMemsetAsync(cursor, 0, NN * 4, stream);
  deg_count<<<EE / 256, 256, 0, stream>>>(edst, deg_i);
  scan_kernel<<<1, 1024, 0, stream>>>(deg_i, offsets);
  inv_deg_k<<<NN / 256, 256, 0, stream>>>(deg_i, inv_deg);
  bucket_k<<<EE / 256, 256, 0, stream>>>(esrc, edst, offsets, cursor, srcs);

  // ---- feature MLP ----
  float* x0 = bufA;               // [N,190]
  float* h1 = bufB;               // [N,380]
  float* h2 = bufC;               // [N,256]
  build_x0<<<(NN * D0_ + 255) / 256, 256, 0, stream>>>(node_features, node_config,
                                                       emb_table, node_ops, x0);
  {
    dim3 g((DX_ + 63) / 64, NN / 64);
    gemm2<<<g, 256, 0, stream>>>(x0, D0_, w1, D0_, D0_,
                                 nullptr, 0, nullptr, 0, 0,
                                 b1, h1, DX_, NN, DX_, 1);
  }
  gln_stats<<<SS, 256, 0, stream>>>(h1, DX_, DX_, seg_mean, seg_inv);
  gln_apply<<<NN, 256, 0, stream>>>(h1, DX_, DX_, seg_mean, seg_inv, g1, be1);

  {
    dim3 g(GIN_ / 64, NN / 64);
    gemm2<<<g, 256, 0, stream>>>(h1, DX_, w2, DX_, DX_,
                                 nullptr, 0, nullptr, 0, 0,
                                 b2, h2, GIN_, NN, GIN_, 1);
  }
  gln_stats<<<SS, 256, 0, stream>>>(h2, GIN_, GIN_, seg_mean, seg_inv);
  gln_apply<<<NN, 256, 0, stream>>>(h2, GIN_, GIN_, seg_mean, seg_inv, g2, be2);

  // ---- SAGE layer 1: agg1(bufA) <- h2(bufC); y1(bufB) ----
  aggregate_k<<<NN, 256, 0, stream>>>(h2, GIN_, bufA, GIN_, GIN_,
                                      offsets, srcs, inv_deg);
  {
    dim3 g(GH_ / 64, NN / 64);
    gemm2<<<g, 256, 0, stream>>>(bufA, GIN_, wl1, GIN_, GIN_,
                                 h2, GIN_, wr1, GIN_, GIN_,
                                 bl1, bufB, GH_, NN, GH_, 0);
  }
  hipMemsetAsync(colsum, 0, 4096, stream);
  pn_stats<<<SS, 512, 0, stream>>>(bufB, colsum, colssq);
  pn_finalize<<<1, 512, 0, stream>>>(colsum, colssq, mu, invd);
  pn_apply<<<NN, 512, 0, stream>>>(bufB, mu, invd, 1);   // x1 in bufB

  // ---- SAGE layer 2: agg2(bufC) <- x1(bufB); y2(bufA) ----
  aggregate_k<<<NN, 512, 0, stream>>>(bufB, GH_, bufC, GH_, GH_,
                                      offsets, srcs, inv_deg);
  {
    dim3 g(GH_ / 64, NN / 64);
    gemm2<<<g, 256, 0, stream>>>(bufC, GH_, wl2, GH_, GH_,
                                 bufB, GH_, wr2, GH_, GH_,
                                 bl2, bufA, GH_, NN, GH_, 0);
  }
  hipMemsetAsync(colsum, 0, 4096, stream);
  pn_stats<<<SS, 512, 0, stream>>>(bufA, colsum, colssq);
  pn_finalize<<<1, 512, 0, stream>>>(colsum, colssq, mu, invd);
  pn_apply<<<NN, 512, 0, stream>>>(bufA, mu, invd, 1);   // x2 in bufA

  // ---- SAGE layer 3: agg3(bufC) <- x2(bufA); y3(bufB) ----
  aggregate_k<<<NN, 512, 0, stream>>>(bufA, GH_, bufC, GH_, GH_,
                                      offsets, srcs, inv_deg);
  {
    dim3 g(GH_ / 64, NN / 64);
    gemm2<<<g, 256, 0, stream>>>(bufC, GH_, wl3, GH_, GH_,
                                 bufA, GH_, wr3, GH_, GH_,
                                 bl3, bufB, GH_, NN, GH_, 0);
  }

  // ---- pooling + head ----
  pool_out<<<SS, 512, 0, stream>>>(bufB, wc, bc, out);
}

// Round 3
// 1125.577 us; speedup vs baseline: 3.2248x; 3.2248x over previous
//
#include <hip/hip_runtime.h>
#include <hip/hip_bf16.h>

// ---- problem constants (fixed by setup_inputs) ----
#define NN   32768
#define EE   262144
#define SS   128
#define NF_  90
#define NC_  36
#define OD_  64
#define D0_  190
#define DX_  380
#define GIN_ 256
#define GH_  512

typedef __attribute__((ext_vector_type(8))) short  s8v;   // 8 bf16 = 4 VGPRs
typedef __attribute__((ext_vector_type(4))) float  f4v;   // 4 fp32

// ---- bf16 helpers (manual, RN) ----
__device__ __forceinline__ float bf2f(unsigned short u) {
  return __uint_as_float(((unsigned)u) << 16);
}
__device__ __forceinline__ unsigned short f2bf(float f) {
  unsigned u = __float_as_uint(f);
  u += 0x7FFFu + ((u >> 16) & 1u);
  return (unsigned short)(u >> 16);
}

// ---------------------------------------------------------------------------
// degree / CSR build
// ---------------------------------------------------------------------------
__global__ void deg_count(const int* __restrict__ dst, int* __restrict__ deg) {
  int e = blockIdx.x * 256 + threadIdx.x;
  if (e < EE) atomicAdd(&deg[dst[e]], 1);
}

__global__ __launch_bounds__(1024) void scan_kernel(const int* __restrict__ deg,
                                                    int* __restrict__ offsets) {
  __shared__ int buf[1024];
  __shared__ int carry_s;
  int tid = threadIdx.x;
  if (tid == 0) carry_s = 0;
  __syncthreads();
  for (int chunk = 0; chunk < NN / 1024; ++chunk) {
    int i = chunk * 1024 + tid;
    int v = deg[i];
    buf[tid] = v;
    __syncthreads();
    for (int d = 1; d < 1024; d <<= 1) {
      int t = (tid >= d) ? buf[tid - d] : 0;
      __syncthreads();
      if (tid >= d) buf[tid] += t;
      __syncthreads();
    }
    int incl = buf[tid];
    int carry = carry_s;
    offsets[i] = carry + incl - v;   // exclusive
    __syncthreads();
    if (tid == 1023) carry_s = carry + incl;
    __syncthreads();
  }
  if (tid == 0) offsets[NN] = carry_s;
}

__global__ void inv_deg_k(const int* __restrict__ deg, float* __restrict__ inv_deg) {
  int n = blockIdx.x * 256 + threadIdx.x;
  if (n < NN) inv_deg[n] = 1.0f / fmaxf((float)deg[n], 1.0f);
}

__global__ void bucket_k(const int* __restrict__ src, const int* __restrict__ dst,
                         const int* __restrict__ offsets, int* __restrict__ cursor,
                         int* __restrict__ srcs) {
  int e = blockIdx.x * 256 + threadIdx.x;
  if (e < EE) {
    int d = dst[e];
    int pos = offsets[d] + atomicAdd(&cursor[d], 1);
    srcs[pos] = src[e];
  }
}

// ---------------------------------------------------------------------------
// weight conversion fp32 -> padded bf16 (zero pad)
// ---------------------------------------------------------------------------
__global__ void conv_pad_bf16(const float* __restrict__ w, unsigned short* __restrict__ wb,
                              int rows_r, int cols_r, int rows_p, int cols_p) {
  int idx = blockIdx.x * 256 + threadIdx.x;
  if (idx >= rows_p * cols_p) return;
  int r = idx / cols_p;
  int c = idx - r * cols_p;
  float v = (r < rows_r && c < cols_r) ? w[r * cols_r + c] : 0.0f;
  wb[idx] = f2bf(v);
}

// ---------------------------------------------------------------------------
// x0 bf16 = concat([nf, ncf, emb[ops]]) padded to 192 cols
// ---------------------------------------------------------------------------
__global__ void build_x0_bf16(const float* __restrict__ nf, const float* __restrict__ ncf,
                              const float* __restrict__ emb, const int* __restrict__ ops,
                              unsigned short* __restrict__ x0) {
  int idx = blockIdx.x * 256 + threadIdx.x;
  if (idx >= NN * 192) return;
  int n = idx / 192;
  int c = idx - n * 192;
  float v;
  if (c < NF_)            v = nf[n * NF_ + c];
  else if (c < NF_ + NC_) v = ncf[n * NC_ + (c - NF_)];
  else if (c < D0_)       v = emb[ops[n] * OD_ + (c - (NF_ + NC_))];
  else                    v = 0.0f;
  x0[idx] = f2bf(v);
}

// ---------------------------------------------------------------------------
// bf16 MFMA GEMM (NT), two-phase: C = act(A1*B1^T + A2*B2^T + bias)
// 128x128 tile, 256 thr = 4 waves (2x2), each wave 64x64 via 4x4 mfma 16x16x32.
// LDS layout per tile: [koff(4)][row(128)][8 bf16] -> 16B frags, conflict-free.
// M = NN fixed multiple of 128; Npad multiple of 128; K multiple of 32.
// ---------------------------------------------------------------------------
__device__ __forceinline__ void stage_tile(const unsigned short* __restrict__ G, int ld,
                                           int base_row, int k0,
                                           unsigned short* __restrict__ lds, int tid) {
#pragma unroll
  for (int i = 0; i < 2; ++i) {
    int c = tid + i * 256;        // 0..511
    int row = c & 127;
    int off = c >> 7;             // 0..3 (k chunk of 8)
    const int4* src = (const int4*)(G + (size_t)(base_row + row) * ld + k0 + off * 8);
    *(int4*)(lds + off * 1024 + row * 8) = *src;
  }
}

__global__ __launch_bounds__(256) void mfma_gemm2(
    const unsigned short* __restrict__ A1, int lda1,
    const unsigned short* __restrict__ B1, int ldb1, int K1,
    const unsigned short* __restrict__ A2, int lda2,
    const unsigned short* __restrict__ B2, int ldb2, int K2,
    const float* __restrict__ bias,
    float* __restrict__ C, int ldc, int Nreal, int act)
{
  __shared__ unsigned short As[4096];
  __shared__ unsigned short Bs[4096];
  int tid = threadIdx.x;
  int lane = tid & 63;
  int w = tid >> 6;
  int wm = (w & 1) * 64;
  int wn = (w >> 1) * 64;
  int bm = blockIdx.y * 128;
  int bn = blockIdx.x * 128;
  int quad = lane >> 4;      // 0..3
  int r16 = lane & 15;

  f4v acc[4][4] = {};

#pragma unroll 1
  for (int ph = 0; ph < 2; ++ph) {
    const unsigned short* A = ph ? A2 : A1;
    const unsigned short* B = ph ? B2 : B1;
    int lda = ph ? lda2 : lda1;
    int ldb = ph ? ldb2 : ldb1;
    int K = ph ? K2 : K1;
    for (int k0 = 0; k0 < K; k0 += 32) {
      stage_tile(A, lda, bm, k0, As, tid);
      stage_tile(B, ldb, bn, k0, Bs, tid);
      __syncthreads();
      s8v af[4], bfr[4];
#pragma unroll
      for (int mi = 0; mi < 4; ++mi)
        af[mi] = *(const s8v*)&As[quad * 1024 + (wm + mi * 16 + r16) * 8];
#pragma unroll
      for (int ni = 0; ni < 4; ++ni)
        bfr[ni] = *(const s8v*)&Bs[quad * 1024 + (wn + ni * 16 + r16) * 8];
#pragma unroll
      for (int mi = 0; mi < 4; ++mi)
#pragma unroll
        for (int ni = 0; ni < 4; ++ni)
          acc[mi][ni] = __builtin_amdgcn_mfma_f32_16x16x32_bf16(
              af[mi], bfr[ni], acc[mi][ni], 0, 0, 0);
      __syncthreads();
    }
  }

  // epilogue: C/D layout col=lane&15, row=quad*4+reg
#pragma unroll
  for (int mi = 0; mi < 4; ++mi) {
    int gm = bm + wm + mi * 16 + quad * 4;
#pragma unroll
    for (int ni = 0; ni < 4; ++ni) {
      int gn = bn + wn + ni * 16 + r16;
      if (gn < Nreal) {
        float bv = bias[gn];
#pragma unroll
        for (int r = 0; r < 4; ++r) {
          float v = acc[mi][ni][r] + bv;
          if (act == 1) v = (v >= 0.0f) ? v : 0.01f * v;
          C[(size_t)(gm + r) * ldc + gn] = v;
        }
      }
    }
  }
}

// ---------------------------------------------------------------------------
// Graph-wise LayerNorm: stats fp32, apply -> bf16 (zero pad to Dp)
// ---------------------------------------------------------------------------
__global__ __launch_bounds__(256) void gln_stats(const float* __restrict__ x, int ld, int D,
                                                 float* __restrict__ seg_mean,
                                                 float* __restrict__ seg_inv) {
  int s = blockIdx.x;
  const float* base = x + (size_t)s * 256 * ld;
  float sum = 0.0f, ssq = 0.0f;
  for (int r = 0; r < 256; ++r) {
    const float* row = base + (size_t)r * ld;
    for (int c = threadIdx.x; c < D; c += 256) {
      float v = row[c];
      sum += v;
      ssq += v * v;
    }
  }
  __shared__ float s1[256], s2[256];
  int tid = threadIdx.x;
  s1[tid] = sum; s2[tid] = ssq;
  __syncthreads();
  for (int off = 128; off > 0; off >>= 1) {
    if (tid < off) { s1[tid] += s1[tid + off]; s2[tid] += s2[tid + off]; }
    __syncthreads();
  }
  if (tid == 0) {
    float cnt = 256.0f * (float)D;
    float m = s1[0] / cnt;
    float var = s2[0] / cnt - m * m;
    seg_mean[s] = m;
    seg_inv[s] = rsqrtf(var + 1e-5f);
  }
}

__global__ __launch_bounds__(256) void gln_apply_bf16(
    const float* __restrict__ x, int ld, int D, int Dp,
    const float* __restrict__ seg_mean, const float* __restrict__ seg_inv,
    const float* __restrict__ g, const float* __restrict__ be,
    unsigned short* __restrict__ out) {
  int r = blockIdx.x;
  int s = r >> 8;
  float m = seg_mean[s];
  float inv = seg_inv[s];
  const float* row = x + (size_t)r * ld;
  unsigned short* orow = out + (size_t)r * Dp;
  for (int c = threadIdx.x; c < Dp; c += 256) {
    float v = (c < D) ? ((row[c] - m) * inv * g[c] + be[c]) : 0.0f;
    orow[c] = f2bf(v);
  }
}

// ---------------------------------------------------------------------------
// neighbor-mean aggregation (bf16 in/out, fp32 accumulate)
// ---------------------------------------------------------------------------
__global__ void aggregate_bf16(const unsigned short* __restrict__ x, int D,
                               unsigned short* __restrict__ agg,
                               const int* __restrict__ offsets,
                               const int* __restrict__ srcs,
                               const float* __restrict__ inv_deg) {
  int n = blockIdx.x;
  int start = offsets[n], end = offsets[n + 1];
  float wgt = inv_deg[n];
  for (int f = threadIdx.x; f < D; f += blockDim.x) {
    float acc = 0.0f;
    for (int e = start; e < end; ++e) {
      acc += bf2f(x[(size_t)srcs[e] * D + f]);
    }
    agg[(size_t)n * D + f] = f2bf(acc * wgt);
  }
}

// ---------------------------------------------------------------------------
// PairNorm: stats on fp32 y; apply -> bf16 (+ReLU)
// ---------------------------------------------------------------------------
__global__ __launch_bounds__(512) void pn_stats(const float* __restrict__ y,
                                                float* __restrict__ colsum,
                                                float* __restrict__ colssq) {
  int f = threadIdx.x;
  int r0 = blockIdx.x * 256;
  float s = 0.0f, ss = 0.0f;
  for (int r = 0; r < 256; ++r) {
    float v = y[(size_t)(r0 + r) * GH_ + f];
    s += v;
    ss += v * v;
  }
  atomicAdd(&colsum[f], s);
  atomicAdd(&colssq[f], ss);
}

__global__ __launch_bounds__(512) void pn_finalize(const float* __restrict__ colsum,
                                                   const float* __restrict__ colssq,
                                                   float* __restrict__ mu,
                                                   float* __restrict__ invd) {
  int f = threadIdx.x;
  float m = colsum[f] / (float)NN;
  mu[f] = m;
  float t = colssq[f] / (float)NN - m * m;
  __shared__ float buf[512];
  buf[f] = t;
  __syncthreads();
  for (int off = 256; off > 0; off >>= 1) {
    if (f < off) buf[f] += buf[f + off];
    __syncthreads();
  }
  if (f == 0) invd[0] = 1.0f / (1e-5f + sqrtf(fmaxf(buf[0], 0.0f)));
}

__global__ __launch_bounds__(512) void pn_apply_bf16(const float* __restrict__ y,
                                                     const float* __restrict__ mu,
                                                     const float* __restrict__ invd,
                                                     unsigned short* __restrict__ xb) {
  int r = blockIdx.x;
  int f = threadIdx.x;
  float v = (y[(size_t)r * GH_ + f] - mu[f]) * invd[0];
  v = fmaxf(v, 0.0f);
  xb[(size_t)r * GH_ + f] = f2bf(v);
}

// ---------------------------------------------------------------------------
// final pooling + head
// ---------------------------------------------------------------------------
__global__ __launch_bounds__(512) void pool_out(const float* __restrict__ y3,
                                                const float* __restrict__ wc,
                                                const float* __restrict__ bc,
                                                float* __restrict__ out) {
  int s = blockIdx.x;
  int f = threadIdx.x;
  const float* base = y3 + (size_t)s * 256 * GH_;
  float acc = 0.0f;
  for (int r = 0; r < 256; ++r) acc += base[(size_t)r * GH_ + f];
  acc *= wc[f];
  __shared__ float buf[512];
  buf[f] = acc;
  __syncthreads();
  for (int off = 256; off > 0; off >>= 1) {
    if (f < off) buf[f] += buf[f + off];
    __syncthreads();
  }
  if (f == 0) out[s] = buf[0] + bc[0];
}

// ---------------------------------------------------------------------------
extern "C" void kernel_launch(void* const* d_in, const int* in_sizes, int n_in,
                              void* d_out, int out_size, void* d_ws, size_t ws_size,
                              hipStream_t stream) {
  const float* node_features = (const float*)d_in[0];
  const float* node_config   = (const float*)d_in[1];
  const float* emb_table     = (const float*)d_in[2];
  const float* w1  = (const float*)d_in[3];
  const float* b1  = (const float*)d_in[4];
  const float* g1  = (const float*)d_in[5];
  const float* be1 = (const float*)d_in[6];
  const float* w2  = (const float*)d_in[7];
  const float* b2  = (const float*)d_in[8];
  const float* g2  = (const float*)d_in[9];
  const float* be2 = (const float*)d_in[10];
  const float* wl1 = (const float*)d_in[11];
  const float* bl1 = (const float*)d_in[12];
  const float* wr1 = (const float*)d_in[13];
  const float* wl2 = (const float*)d_in[14];
  const float* bl2 = (const float*)d_in[15];
  const float* wr2 = (const float*)d_in[16];
  const float* wl3 = (const float*)d_in[17];
  const float* bl3 = (const float*)d_in[18];
  const float* wr3 = (const float*)d_in[19];
  const float* wc  = (const float*)d_in[20];
  const float* bc  = (const float*)d_in[21];
  const int* node_ops = (const int*)d_in[22];
  const int* edges    = (const int*)d_in[23];
  float* out = (float*)d_out;

  char* ws = (char*)d_ws;
  size_t off = 0;
  auto alloc = [&](size_t bytes) -> void* {
    void* p = ws + off;
    off += (bytes + 255) & ~(size_t)255;
    return p;
  };

  int*   deg_i   = (int*)alloc(NN * 4);
  int*   cursor  = (int*)alloc(NN * 4);
  int*   offsets = (int*)alloc((NN + 1) * 4);
  int*   srcs    = (int*)alloc(EE * 4);
  float* inv_deg = (float*)alloc(NN * 4);
  float* seg_mean= (float*)alloc(SS * 4);
  float* seg_inv = (float*)alloc(SS * 4);
  float* colsum  = (float*)alloc(512 * 4);   // colssq directly follows (4KB memset)
  float* colssq  = (float*)alloc(512 * 4);
  float* mu      = (float*)alloc(512 * 4);
  float* invd    = (float*)alloc(256);
  // bf16 weights (padded)
  unsigned short* w1b  = (unsigned short*)alloc((size_t)384 * 192 * 2);
  unsigned short* w2b  = (unsigned short*)alloc((size_t)256 * 384 * 2);
  unsigned short* wl1b = (unsigned short*)alloc((size_t)512 * 256 * 2);
  unsigned short* wr1b = (unsigned short*)alloc((size_t)512 * 256 * 2);
  unsigned short* wl2b = (unsigned short*)alloc((size_t)512 * 512 * 2);
  unsigned short* wr2b = (unsigned short*)alloc((size_t)512 * 512 * 2);
  unsigned short* wl3b = (unsigned short*)alloc((size_t)512 * 512 * 2);
  unsigned short* wr3b = (unsigned short*)alloc((size_t)512 * 512 * 2);
  // fp32 GEMM output slab + three rotating bf16 slabs
  float*          Y    = (float*)alloc((size_t)NN * 512 * 4);          // 67 MB
  unsigned short* BF1  = (unsigned short*)alloc((size_t)NN * 512 * 2); // 33.5 MB
  unsigned short* BF2  = (unsigned short*)alloc((size_t)NN * 512 * 2);
  unsigned short* BF3  = (unsigned short*)alloc((size_t)NN * 512 * 2);

  const int* esrc = edges;
  const int* edst = edges + EE;

  // ---- CSR build ----
  hipMemsetAsync(deg_i, 0, NN * 4, stream);
  hipMemsetAsync(cursor, 0, NN * 4, stream);
  deg_count<<<EE / 256, 256, 0, stream>>>(edst, deg_i);
  scan_kernel<<<1, 1024, 0, stream>>>(deg_i, offsets);
  inv_deg_k<<<NN / 256, 256, 0, stream>>>(deg_i, inv_deg);
  bucket_k<<<EE / 256, 256, 0, stream>>>(esrc, edst, offsets, cursor, srcs);

  // ---- weight conversion ----
  conv_pad_bf16<<<(384 * 192 + 255) / 256, 256, 0, stream>>>(w1, w1b, DX_, D0_, 384, 192);
  conv_pad_bf16<<<(256 * 384 + 255) / 256, 256, 0, stream>>>(w2, w2b, GIN_, DX_, 256, 384);
  conv_pad_bf16<<<(512 * 256 + 255) / 256, 256, 0, stream>>>(wl1, wl1b, 512, 256, 512, 256);
  conv_pad_bf16<<<(512 * 256 + 255) / 256, 256, 0, stream>>>(wr1, wr1b, 512, 256, 512, 256);
  conv_pad_bf16<<<(512 * 512 + 255) / 256, 256, 0, stream>>>(wl2, wl2b, 512, 512, 512, 512);
  conv_pad_bf16<<<(512 * 512 + 255) / 256, 256, 0, stream>>>(wr2, wr2b, 512, 512, 512, 512);
  conv_pad_bf16<<<(512 * 512 + 255) / 256, 256, 0, stream>>>(wl3, wl3b, 512, 512, 512, 512);
  conv_pad_bf16<<<(512 * 512 + 255) / 256, 256, 0, stream>>>(wr3, wr3b, 512, 512, 512, 512);

  // ---- feature MLP ----
  build_x0_bf16<<<(NN * 192 + 255) / 256, 256, 0, stream>>>(node_features, node_config,
                                                            emb_table, node_ops, BF1);
  {  // h1f = leaky(x0 @ w1^T + b1) : [N,380] in Y (ld 384)
    dim3 g(384 / 128, NN / 128);
    mfma_gemm2<<<g, 256, 0, stream>>>(BF1, 192, w1b, 192, 192,
                                      nullptr, 0, nullptr, 0, 0,
                                      b1, Y, 384, DX_, 1);
  }
  gln_stats<<<SS, 256, 0, stream>>>(Y, 384, DX_, seg_mean, seg_inv);
  gln_apply_bf16<<<NN, 256, 0, stream>>>(Y, 384, DX_, 384, seg_mean, seg_inv, g1, be1, BF2);

  {  // h2f = leaky(h1 @ w2^T + b2) : [N,256] in Y (ld 256)
    dim3 g(256 / 128, NN / 128);
    mfma_gemm2<<<g, 256, 0, stream>>>(BF2, 384, w2b, 384, 384,
                                      nullptr, 0, nullptr, 0, 0,
                                      b2, Y, 256, GIN_, 1);
  }
  gln_stats<<<SS, 256, 0, stream>>>(Y, 256, GIN_, seg_mean, seg_inv);
  gln_apply_bf16<<<NN, 256, 0, stream>>>(Y, 256, GIN_, 256, seg_mean, seg_inv, g2, be2, BF3);

  // ---- SAGE layer 1: agg(BF1) <- h2(BF3); y1 = agg@wl1 + h2@wr1 ----
  aggregate_bf16<<<NN, 256, 0, stream>>>(BF3, GIN_, BF1, offsets, srcs, inv_deg);
  {
    dim3 g(512 / 128, NN / 128);
    mfma_gemm2<<<g, 256, 0, stream>>>(BF1, 256, wl1b, 256, 256,
                                      BF3, 256, wr1b, 256, 256,
                                      bl1, Y, 512, GH_, 0);
  }
  hipMemsetAsync(colsum, 0, 4096, stream);
  pn_stats<<<SS, 512, 0, stream>>>(Y, colsum, colssq);
  pn_finalize<<<1, 512, 0, stream>>>(colsum, colssq, mu, invd);
  pn_apply_bf16<<<NN, 512, 0, stream>>>(Y, mu, invd, BF2);   // x1 -> BF2

  // ---- SAGE layer 2: agg(BF1) <- x1(BF2) ----
  aggregate_bf16<<<NN, 256, 0, stream>>>(BF2, GH_, BF1, offsets, srcs, inv_deg);
  {
    dim3 g(512 / 128, NN / 128);
    mfma_gemm2<<<g, 256, 0, stream>>>(BF1, 512, wl2b, 512, 512,
                                      BF2, 512, wr2b, 512, 512,
                                      bl2, Y, 512, GH_, 0);
  }
  hipMemsetAsync(colsum, 0, 4096, stream);
  pn_stats<<<SS, 512, 0, stream>>>(Y, colsum, colssq);
  pn_finalize<<<1, 512, 0, stream>>>(colsum, colssq, mu, invd);
  pn_apply_bf16<<<NN, 512, 0, stream>>>(Y, mu, invd, BF3);   // x2 -> BF3

  // ---- SAGE layer 3: agg(BF1) <- x2(BF3) ----
  aggregate_bf16<<<NN, 256, 0, stream>>>(BF3, GH_, BF1, offsets, srcs, inv_deg);
  {
    dim3 g(512 / 128, NN / 128);
    mfma_gemm2<<<g, 256, 0, stream>>>(BF1, 512, wl3b, 512, 512,
                                      BF3, 512, wr3b, 512, 512,
                                      bl3, Y, 512, GH_, 0);
  }

  // ---- pooling + head ----
  pool_out<<<SS, 512, 0, stream>>>(Y, wc, bc, out);
}

// Round 4
// 875.214 us; speedup vs baseline: 4.1472x; 1.2861x over previous
//
#include <hip/hip_runtime.h>
#include <hip/hip_bf16.h>

// ---- problem constants (fixed by setup_inputs) ----
#define NN   32768
#define EE   262144
#define SS   128
#define NF_  90
#define NC_  36
#define OD_  64
#define D0_  190
#define DX_  380
#define GIN_ 256
#define GH_  512

typedef __attribute__((ext_vector_type(8))) short  s8v;   // 8 bf16 = 4 VGPRs
typedef __attribute__((ext_vector_type(4))) float  f4v;   // 4 fp32

typedef const __attribute__((address_space(1))) void* gas_ptr;
typedef __attribute__((address_space(3))) void*       las_ptr;

// ---- bf16 helpers (manual, RN) ----
__device__ __forceinline__ float bf2f(unsigned short u) {
  return __uint_as_float(((unsigned)u) << 16);
}
__device__ __forceinline__ unsigned short f2bf(float f) {
  unsigned u = __float_as_uint(f);
  u += 0x7FFFu + ((u >> 16) & 1u);
  return (unsigned short)(u >> 16);
}

// ---------------------------------------------------------------------------
// degree / CSR build
// ---------------------------------------------------------------------------
__global__ void deg_count(const int* __restrict__ dst, int* __restrict__ deg) {
  int e = blockIdx.x * 256 + threadIdx.x;
  if (e < EE) atomicAdd(&deg[dst[e]], 1);
}

__global__ __launch_bounds__(1024) void scan_kernel(const int* __restrict__ deg,
                                                    int* __restrict__ offsets) {
  __shared__ int buf[1024];
  __shared__ int carry_s;
  int tid = threadIdx.x;
  if (tid == 0) carry_s = 0;
  __syncthreads();
  for (int chunk = 0; chunk < NN / 1024; ++chunk) {
    int i = chunk * 1024 + tid;
    int v = deg[i];
    buf[tid] = v;
    __syncthreads();
    for (int d = 1; d < 1024; d <<= 1) {
      int t = (tid >= d) ? buf[tid - d] : 0;
      __syncthreads();
      if (tid >= d) buf[tid] += t;
      __syncthreads();
    }
    int incl = buf[tid];
    int carry = carry_s;
    offsets[i] = carry + incl - v;   // exclusive
    __syncthreads();
    if (tid == 1023) carry_s = carry + incl;
    __syncthreads();
  }
  if (tid == 0) offsets[NN] = carry_s;
}

__global__ void inv_deg_k(const int* __restrict__ deg, float* __restrict__ inv_deg) {
  int n = blockIdx.x * 256 + threadIdx.x;
  if (n < NN) inv_deg[n] = 1.0f / fmaxf((float)deg[n], 1.0f);
}

__global__ void bucket_k(const int* __restrict__ src, const int* __restrict__ dst,
                         const int* __restrict__ offsets, int* __restrict__ cursor,
                         int* __restrict__ srcs) {
  int e = blockIdx.x * 256 + threadIdx.x;
  if (e < EE) {
    int d = dst[e];
    int pos = offsets[d] + atomicAdd(&cursor[d], 1);
    srcs[pos] = src[e];
  }
}

// ---------------------------------------------------------------------------
// weight conversion fp32 -> padded bf16 (zero pad)
// ---------------------------------------------------------------------------
__global__ void conv_pad_bf16(const float* __restrict__ w, unsigned short* __restrict__ wb,
                              int rows_r, int cols_r, int rows_p, int cols_p) {
  int idx = blockIdx.x * 256 + threadIdx.x;
  if (idx >= rows_p * cols_p) return;
  int r = idx / cols_p;
  int c = idx - r * cols_p;
  float v = (r < rows_r && c < cols_r) ? w[r * cols_r + c] : 0.0f;
  wb[idx] = f2bf(v);
}

// ---------------------------------------------------------------------------
// x0 bf16 = concat([nf, ncf, emb[ops]]) padded to 192 cols
// ---------------------------------------------------------------------------
__global__ void build_x0_bf16(const float* __restrict__ nf, const float* __restrict__ ncf,
                              const float* __restrict__ emb, const int* __restrict__ ops,
                              unsigned short* __restrict__ x0) {
  int idx = blockIdx.x * 256 + threadIdx.x;
  if (idx >= NN * 192) return;
  int n = idx / 192;
  int c = idx - n * 192;
  float v;
  if (c < NF_)            v = nf[n * NF_ + c];
  else if (c < NF_ + NC_) v = ncf[n * NC_ + (c - NF_)];
  else if (c < D0_)       v = emb[ops[n] * OD_ + (c - (NF_ + NC_))];
  else                    v = 0.0f;
  x0[idx] = f2bf(v);
}

// ---------------------------------------------------------------------------
// bf16 MFMA GEMM (NT), two-phase: C = act(A1*B1^T + A2*B2^T + bias)
// 128x128 tile, 256 thr = 4 waves (2x2), each wave 64x64 via 4x4 mfma 16x16x32.
// LDS layout per tile: [koff(4)][row(128)][8 bf16]; staged with async
// global_load_lds width=16 (wave-uniform base + lane*16 satisfied by layout).
// ---------------------------------------------------------------------------
__device__ __forceinline__ void stage_tile_async(const unsigned short* __restrict__ G, int ld,
                                                 int base_row, int k0,
                                                 unsigned short* __restrict__ lds, int tid) {
#pragma unroll
  for (int i = 0; i < 2; ++i) {
    int c = tid + i * 256;        // 0..511
    int row = c & 127;
    int off = c >> 7;             // 0..3 (k chunk of 8 bf16)
    const unsigned short* src = G + (size_t)(base_row + row) * ld + k0 + off * 8;
    unsigned short* dst = lds + off * 1024 + row * 8;
    __builtin_amdgcn_global_load_lds((gas_ptr)(const void*)src, (las_ptr)(void*)dst,
                                     16, 0, 0);
  }
}

__global__ __launch_bounds__(256) void mfma_gemm2(
    const unsigned short* __restrict__ A1, int lda1,
    const unsigned short* __restrict__ B1, int ldb1, int K1,
    const unsigned short* __restrict__ A2, int lda2,
    const unsigned short* __restrict__ B2, int ldb2, int K2,
    const float* __restrict__ bias,
    float* __restrict__ C, int ldc, int Nreal, int act)
{
  __shared__ unsigned short As[4096];
  __shared__ unsigned short Bs[4096];
  int tid = threadIdx.x;
  int lane = tid & 63;
  int w = tid >> 6;
  int wm = (w & 1) * 64;
  int wn = (w >> 1) * 64;
  int bm = blockIdx.y * 128;
  int bn = blockIdx.x * 128;
  int quad = lane >> 4;      // 0..3
  int r16 = lane & 15;

  f4v acc[4][4] = {};

#pragma unroll 1
  for (int ph = 0; ph < 2; ++ph) {
    const unsigned short* A = ph ? A2 : A1;
    const unsigned short* B = ph ? B2 : B1;
    int lda = ph ? lda2 : lda1;
    int ldb = ph ? ldb2 : ldb1;
    int K = ph ? K2 : K1;
    for (int k0 = 0; k0 < K; k0 += 32) {
      stage_tile_async(A, lda, bm, k0, As, tid);
      stage_tile_async(B, ldb, bn, k0, Bs, tid);
      __syncthreads();
      s8v af[4], bfr[4];
#pragma unroll
      for (int mi = 0; mi < 4; ++mi)
        af[mi] = *(const s8v*)&As[quad * 1024 + (wm + mi * 16 + r16) * 8];
#pragma unroll
      for (int ni = 0; ni < 4; ++ni)
        bfr[ni] = *(const s8v*)&Bs[quad * 1024 + (wn + ni * 16 + r16) * 8];
#pragma unroll
      for (int mi = 0; mi < 4; ++mi)
#pragma unroll
        for (int ni = 0; ni < 4; ++ni)
          acc[mi][ni] = __builtin_amdgcn_mfma_f32_16x16x32_bf16(
              af[mi], bfr[ni], acc[mi][ni], 0, 0, 0);
      __syncthreads();
    }
  }

  // epilogue: C/D layout col=lane&15, row=quad*4+reg
#pragma unroll
  for (int mi = 0; mi < 4; ++mi) {
    int gm = bm + wm + mi * 16 + quad * 4;
#pragma unroll
    for (int ni = 0; ni < 4; ++ni) {
      int gn = bn + wn + ni * 16 + r16;
      if (gn < Nreal) {
        float bv = bias[gn];
#pragma unroll
        for (int r = 0; r < 4; ++r) {
          float v = acc[mi][ni][r] + bv;
          if (act == 1) v = (v >= 0.0f) ? v : 0.01f * v;
          C[(size_t)(gm + r) * ldc + gn] = v;
        }
      }
    }
  }
}

// ---------------------------------------------------------------------------
// Graph-wise LayerNorm: parallel partial stats (1024 blocks x 32 rows) +
// finalize; apply -> bf16 (zero pad to Dp)
// ---------------------------------------------------------------------------
__global__ __launch_bounds__(256) void gln_stats_part(const float* __restrict__ x,
                                                      int ld, int D,
                                                      float* __restrict__ seg_sum,
                                                      float* __restrict__ seg_ssq) {
  int r0 = blockIdx.x * 32;      // 32 rows per block; never crosses a segment
  int s = r0 >> 8;
  float sum = 0.0f, ssq = 0.0f;
  for (int r = r0; r < r0 + 32; ++r) {
    const float* row = x + (size_t)r * ld;
    for (int c = threadIdx.x; c < D; c += 256) {
      float v = row[c];
      sum += v;
      ssq += v * v;
    }
  }
  __shared__ float s1[256], s2[256];
  int tid = threadIdx.x;
  s1[tid] = sum; s2[tid] = ssq;
  __syncthreads();
  for (int off = 128; off > 0; off >>= 1) {
    if (tid < off) { s1[tid] += s1[tid + off]; s2[tid] += s2[tid + off]; }
    __syncthreads();
  }
  if (tid == 0) {
    atomicAdd(&seg_sum[s], s1[0]);
    atomicAdd(&seg_ssq[s], s2[0]);
  }
}

__global__ void gln_finalize(const float* __restrict__ seg_sum,
                             const float* __restrict__ seg_ssq, int D,
                             float* __restrict__ seg_mean,
                             float* __restrict__ seg_inv) {
  int s = threadIdx.x;  // 128
  float cnt = 256.0f * (float)D;
  float m = seg_sum[s] / cnt;
  float var = seg_ssq[s] / cnt - m * m;
  seg_mean[s] = m;
  seg_inv[s] = rsqrtf(var + 1e-5f);
}

__global__ __launch_bounds__(256) void gln_apply_bf16(
    const float* __restrict__ x, int ld, int D, int Dp,
    const float* __restrict__ seg_mean, const float* __restrict__ seg_inv,
    const float* __restrict__ g, const float* __restrict__ be,
    unsigned short* __restrict__ out) {
  int r = blockIdx.x;
  int s = r >> 8;
  float m = seg_mean[s];
  float inv = seg_inv[s];
  const float* row = x + (size_t)r * ld;
  unsigned short* orow = out + (size_t)r * Dp;
  for (int c = threadIdx.x; c < Dp; c += 256) {
    float v = (c < D) ? ((row[c] - m) * inv * g[c] + be[c]) : 0.0f;
    orow[c] = f2bf(v);
  }
}

// ---------------------------------------------------------------------------
// neighbor-mean aggregation (bf16 in/out, fp32 accumulate, uint vector lanes)
// blockDim = D/2; one uint (2 bf16) per thread
// ---------------------------------------------------------------------------
__global__ void aggregate_bf16_v(const unsigned short* __restrict__ x, int D,
                                 unsigned short* __restrict__ agg,
                                 const int* __restrict__ offsets,
                                 const int* __restrict__ srcs,
                                 const float* __restrict__ inv_deg) {
  int n = blockIdx.x;
  int f2 = threadIdx.x;
  int D2 = D >> 1;
  int start = offsets[n], end = offsets[n + 1];
  float wgt = inv_deg[n];
  const unsigned* xb = (const unsigned*)x;
  float a0 = 0.0f, a1 = 0.0f;
  for (int e = start; e < end; ++e) {
    unsigned v = xb[(size_t)srcs[e] * D2 + f2];
    a0 += bf2f((unsigned short)(v & 0xffffu));
    a1 += bf2f((unsigned short)(v >> 16));
  }
  unsigned short lo = f2bf(a0 * wgt);
  unsigned short hi = f2bf(a1 * wgt);
  ((unsigned*)agg)[(size_t)n * D2 + f2] = ((unsigned)hi << 16) | (unsigned)lo;
}

// ---------------------------------------------------------------------------
// PairNorm: parallel column stats (512 blocks x 64 rows) -> finalize ->
// apply -> bf16 (+ReLU)
// ---------------------------------------------------------------------------
__global__ __launch_bounds__(512) void pn_stats_part(const float* __restrict__ y,
                                                     float* __restrict__ colsum,
                                                     float* __restrict__ colssq) {
  int f = threadIdx.x;
  int r0 = blockIdx.x * 64;
  float s = 0.0f, ss = 0.0f;
  for (int r = r0; r < r0 + 64; ++r) {
    float v = y[(size_t)r * GH_ + f];
    s += v;
    ss += v * v;
  }
  atomicAdd(&colsum[f], s);
  atomicAdd(&colssq[f], ss);
}

__global__ __launch_bounds__(512) void pn_finalize(const float* __restrict__ colsum,
                                                   const float* __restrict__ colssq,
                                                   float* __restrict__ mu,
                                                   float* __restrict__ invd) {
  int f = threadIdx.x;
  float m = colsum[f] / (float)NN;
  mu[f] = m;
  float t = colssq[f] / (float)NN - m * m;
  __shared__ float buf[512];
  buf[f] = t;
  __syncthreads();
  for (int off = 256; off > 0; off >>= 1) {
    if (f < off) buf[f] += buf[f + off];
    __syncthreads();
  }
  if (f == 0) invd[0] = 1.0f / (1e-5f + sqrtf(fmaxf(buf[0], 0.0f)));
}

__global__ __launch_bounds__(512) void pn_apply_bf16(const float* __restrict__ y,
                                                     const float* __restrict__ mu,
                                                     const float* __restrict__ invd,
                                                     unsigned short* __restrict__ xb) {
  int r = blockIdx.x;
  int f = threadIdx.x;
  float v = (y[(size_t)r * GH_ + f] - mu[f]) * invd[0];
  v = fmaxf(v, 0.0f);
  xb[(size_t)r * GH_ + f] = f2bf(v);
}

// ---------------------------------------------------------------------------
// final pooling + head: out[s] = sum_{r in seg s} dot(y3[r], wc) + bc
// ---------------------------------------------------------------------------
__global__ void init_out(float* __restrict__ out, const float* __restrict__ bc) {
  int s = threadIdx.x;
  if (s < SS) out[s] = bc[0];
}

__global__ __launch_bounds__(512) void pool_part(const float* __restrict__ y3,
                                                 const float* __restrict__ wc,
                                                 float* __restrict__ out) {
  int f = threadIdx.x;
  int r0 = blockIdx.x * 32;
  int s = r0 >> 8;
  float acc = 0.0f;
  for (int r = r0; r < r0 + 32; ++r) acc += y3[(size_t)r * GH_ + f];
  acc *= wc[f];
  __shared__ float buf[512];
  buf[f] = acc;
  __syncthreads();
  for (int off = 256; off > 0; off >>= 1) {
    if (f < off) buf[f] += buf[f + off];
    __syncthreads();
  }
  if (f == 0) atomicAdd(&out[s], buf[0]);
}

// ---------------------------------------------------------------------------
extern "C" void kernel_launch(void* const* d_in, const int* in_sizes, int n_in,
                              void* d_out, int out_size, void* d_ws, size_t ws_size,
                              hipStream_t stream) {
  const float* node_features = (const float*)d_in[0];
  const float* node_config   = (const float*)d_in[1];
  const float* emb_table     = (const float*)d_in[2];
  const float* w1  = (const float*)d_in[3];
  const float* b1  = (const float*)d_in[4];
  const float* g1  = (const float*)d_in[5];
  const float* be1 = (const float*)d_in[6];
  const float* w2  = (const float*)d_in[7];
  const float* b2  = (const float*)d_in[8];
  const float* g2  = (const float*)d_in[9];
  const float* be2 = (const float*)d_in[10];
  const float* wl1 = (const float*)d_in[11];
  const float* bl1 = (const float*)d_in[12];
  const float* wr1 = (const float*)d_in[13];
  const float* wl2 = (const float*)d_in[14];
  const float* bl2 = (const float*)d_in[15];
  const float* wr2 = (const float*)d_in[16];
  const float* wl3 = (const float*)d_in[17];
  const float* bl3 = (const float*)d_in[18];
  const float* wr3 = (const float*)d_in[19];
  const float* wc  = (const float*)d_in[20];
  const float* bc  = (const float*)d_in[21];
  const int* node_ops = (const int*)d_in[22];
  const int* edges    = (const int*)d_in[23];
  float* out = (float*)d_out;

  char* ws = (char*)d_ws;
  size_t off = 0;
  auto alloc = [&](size_t bytes) -> void* {
    void* p = ws + off;
    off += (bytes + 255) & ~(size_t)255;
    return p;
  };

  int*   deg_i   = (int*)alloc(NN * 4);
  int*   cursor  = (int*)alloc(NN * 4);
  int*   offsets = (int*)alloc((NN + 1) * 4);
  int*   srcs    = (int*)alloc(EE * 4);
  float* inv_deg = (float*)alloc(NN * 4);
  float* seg_sum = (float*)alloc(SS * 4);   // 512B; seg_ssq follows contiguously
  float* seg_ssq = (float*)alloc(SS * 4);
  float* seg_mean= (float*)alloc(SS * 4);
  float* seg_inv = (float*)alloc(SS * 4);
  float* colsum  = (float*)alloc(512 * 4);  // colssq directly follows (4KB memset)
  float* colssq  = (float*)alloc(512 * 4);
  float* mu      = (float*)alloc(512 * 4);
  float* invd    = (float*)alloc(256);
  // bf16 weights (padded)
  unsigned short* w1b  = (unsigned short*)alloc((size_t)384 * 192 * 2);
  unsigned short* w2b  = (unsigned short*)alloc((size_t)256 * 384 * 2);
  unsigned short* wl1b = (unsigned short*)alloc((size_t)512 * 256 * 2);
  unsigned short* wr1b = (unsigned short*)alloc((size_t)512 * 256 * 2);
  unsigned short* wl2b = (unsigned short*)alloc((size_t)512 * 512 * 2);
  unsigned short* wr2b = (unsigned short*)alloc((size_t)512 * 512 * 2);
  unsigned short* wl3b = (unsigned short*)alloc((size_t)512 * 512 * 2);
  unsigned short* wr3b = (unsigned short*)alloc((size_t)512 * 512 * 2);
  // fp32 GEMM output slab + three rotating bf16 slabs
  float*          Y    = (float*)alloc((size_t)NN * 512 * 4);          // 67 MB
  unsigned short* BF1  = (unsigned short*)alloc((size_t)NN * 512 * 2); // 33.5 MB
  unsigned short* BF2  = (unsigned short*)alloc((size_t)NN * 512 * 2);
  unsigned short* BF3  = (unsigned short*)alloc((size_t)NN * 512 * 2);

  const int* esrc = edges;
  const int* edst = edges + EE;

  // ---- CSR build ----
  hipMemsetAsync(deg_i, 0, NN * 4, stream);
  hipMemsetAsync(cursor, 0, NN * 4, stream);
  deg_count<<<EE / 256, 256, 0, stream>>>(edst, deg_i);
  scan_kernel<<<1, 1024, 0, stream>>>(deg_i, offsets);
  inv_deg_k<<<NN / 256, 256, 0, stream>>>(deg_i, inv_deg);
  bucket_k<<<EE / 256, 256, 0, stream>>>(esrc, edst, offsets, cursor, srcs);

  // ---- weight conversion ----
  conv_pad_bf16<<<(384 * 192 + 255) / 256, 256, 0, stream>>>(w1, w1b, DX_, D0_, 384, 192);
  conv_pad_bf16<<<(256 * 384 + 255) / 256, 256, 0, stream>>>(w2, w2b, GIN_, DX_, 256, 384);
  conv_pad_bf16<<<(512 * 256 + 255) / 256, 256, 0, stream>>>(wl1, wl1b, 512, 256, 512, 256);
  conv_pad_bf16<<<(512 * 256 + 255) / 256, 256, 0, stream>>>(wr1, wr1b, 512, 256, 512, 256);
  conv_pad_bf16<<<(512 * 512 + 255) / 256, 256, 0, stream>>>(wl2, wl2b, 512, 512, 512, 512);
  conv_pad_bf16<<<(512 * 512 + 255) / 256, 256, 0, stream>>>(wr2, wr2b, 512, 512, 512, 512);
  conv_pad_bf16<<<(512 * 512 + 255) / 256, 256, 0, stream>>>(wl3, wl3b, 512, 512, 512, 512);
  conv_pad_bf16<<<(512 * 512 + 255) / 256, 256, 0, stream>>>(wr3, wr3b, 512, 512, 512, 512);

  // ---- feature MLP ----
  build_x0_bf16<<<(NN * 192 + 255) / 256, 256, 0, stream>>>(node_features, node_config,
                                                            emb_table, node_ops, BF1);
  {  // h1f = leaky(x0 @ w1^T + b1) : [N,380] in Y (ld 384)
    dim3 g(384 / 128, NN / 128);
    mfma_gemm2<<<g, 256, 0, stream>>>(BF1, 192, w1b, 192, 192,
                                      nullptr, 0, nullptr, 0, 0,
                                      b1, Y, 384, DX_, 1);
  }
  hipMemsetAsync(seg_sum, 0, 1024, stream);   // seg_sum + seg_ssq
  gln_stats_part<<<NN / 32, 256, 0, stream>>>(Y, 384, DX_, seg_sum, seg_ssq);
  gln_finalize<<<1, SS, 0, stream>>>(seg_sum, seg_ssq, DX_, seg_mean, seg_inv);
  gln_apply_bf16<<<NN, 256, 0, stream>>>(Y, 384, DX_, 384, seg_mean, seg_inv, g1, be1, BF2);

  {  // h2f = leaky(h1 @ w2^T + b2) : [N,256] in Y (ld 256)
    dim3 g(256 / 128, NN / 128);
    mfma_gemm2<<<g, 256, 0, stream>>>(BF2, 384, w2b, 384, 384,
                                      nullptr, 0, nullptr, 0, 0,
                                      b2, Y, 256, GIN_, 1);
  }
  hipMemsetAsync(seg_sum, 0, 1024, stream);
  gln_stats_part<<<NN / 32, 256, 0, stream>>>(Y, 256, GIN_, seg_sum, seg_ssq);
  gln_finalize<<<1, SS, 0, stream>>>(seg_sum, seg_ssq, GIN_, seg_mean, seg_inv);
  gln_apply_bf16<<<NN, 256, 0, stream>>>(Y, 256, GIN_, 256, seg_mean, seg_inv, g2, be2, BF3);

  // ---- SAGE layer 1: agg(BF1) <- h2(BF3); y1 = agg@wl1 + h2@wr1 ----
  aggregate_bf16_v<<<NN, GIN_ / 2, 0, stream>>>(BF3, GIN_, BF1, offsets, srcs, inv_deg);
  {
    dim3 g(512 / 128, NN / 128);
    mfma_gemm2<<<g, 256, 0, stream>>>(BF1, 256, wl1b, 256, 256,
                                      BF3, 256, wr1b, 256, 256,
                                      bl1, Y, 512, GH_, 0);
  }
  hipMemsetAsync(colsum, 0, 4096, stream);
  pn_stats_part<<<NN / 64, 512, 0, stream>>>(Y, colsum, colssq);
  pn_finalize<<<1, 512, 0, stream>>>(colsum, colssq, mu, invd);
  pn_apply_bf16<<<NN, 512, 0, stream>>>(Y, mu, invd, BF2);   // x1 -> BF2

  // ---- SAGE layer 2: agg(BF1) <- x1(BF2) ----
  aggregate_bf16_v<<<NN, GH_ / 2, 0, stream>>>(BF2, GH_, BF1, offsets, srcs, inv_deg);
  {
    dim3 g(512 / 128, NN / 128);
    mfma_gemm2<<<g, 256, 0, stream>>>(BF1, 512, wl2b, 512, 512,
                                      BF2, 512, wr2b, 512, 512,
                                      bl2, Y, 512, GH_, 0);
  }
  hipMemsetAsync(colsum, 0, 4096, stream);
  pn_stats_part<<<NN / 64, 512, 0, stream>>>(Y, colsum, colssq);
  pn_finalize<<<1, 512, 0, stream>>>(colsum, colssq, mu, invd);
  pn_apply_bf16<<<NN, 512, 0, stream>>>(Y, mu, invd, BF3);   // x2 -> BF3

  // ---- SAGE layer 3: agg(BF1) <- x2(BF3) ----
  aggregate_bf16_v<<<NN, GH_ / 2, 0, stream>>>(BF3, GH_, BF1, offsets, srcs, inv_deg);
  {
    dim3 g(512 / 128, NN / 128);
    mfma_gemm2<<<g, 256, 0, stream>>>(BF1, 512, wl3b, 512, 512,
                                      BF3, 512, wr3b, 512, 512,
                                      bl3, Y, 512, GH_, 0);
  }

  // ---- pooling + head ----
  init_out<<<1, SS, 0, stream>>>(out, bc);
  pool_part<<<NN / 32, 512, 0, stream>>>(Y, wc, out);
}

// Round 5
// 663.698 us; speedup vs baseline: 5.4689x; 1.3187x over previous
//
#include <hip/hip_runtime.h>
#include <hip/hip_bf16.h>

// ---- problem constants (fixed by setup_inputs) ----
#define NN   32768
#define EE   262144
#define SS   128
#define NF_  90
#define NC_  36
#define OD_  64
#define D0_  190
#define DX_  380
#define GIN_ 256
#define GH_  512

typedef __attribute__((ext_vector_type(8))) short  s8v;   // 8 bf16 = 4 VGPRs
typedef __attribute__((ext_vector_type(4))) float  f4v;   // 4 fp32

typedef const __attribute__((address_space(1))) void* gas_ptr;
typedef __attribute__((address_space(3))) void*       las_ptr;

// ---- bf16 helpers (manual, RN) ----
__device__ __forceinline__ float bf2f(unsigned short u) {
  return __uint_as_float(((unsigned)u) << 16);
}
__device__ __forceinline__ unsigned short f2bf(float f) {
  unsigned u = __float_as_uint(f);
  u += 0x7FFFu + ((u >> 16) & 1u);
  return (unsigned short)(u >> 16);
}

// ---------------------------------------------------------------------------
// degree / CSR build (parallel 3-phase scan)
// ---------------------------------------------------------------------------
__global__ void deg_count(const int* __restrict__ dst, int* __restrict__ deg) {
  int e = blockIdx.x * 256 + threadIdx.x;
  if (e < EE) atomicAdd(&deg[dst[e]], 1);
}

__global__ void inv_deg_k(const int* __restrict__ deg, float* __restrict__ inv_deg) {
  int n = blockIdx.x * 256 + threadIdx.x;
  if (n < NN) inv_deg[n] = 1.0f / fmaxf((float)deg[n], 1.0f);
}

__global__ __launch_bounds__(256) void blk_sum_k(const int* __restrict__ deg,
                                                 int* __restrict__ bsum) {
  __shared__ int buf[256];
  int tid = threadIdx.x;
  buf[tid] = deg[blockIdx.x * 256 + tid];
  __syncthreads();
  for (int off = 128; off > 0; off >>= 1) {
    if (tid < off) buf[tid] += buf[tid + off];
    __syncthreads();
  }
  if (tid == 0) bsum[blockIdx.x] = buf[0];
}

__global__ __launch_bounds__(128) void blk_scan_k(const int* __restrict__ bsum,
                                                  int* __restrict__ boff) {
  __shared__ int buf[128];
  int tid = threadIdx.x;
  int v = bsum[tid];
  buf[tid] = v;
  __syncthreads();
  for (int d = 1; d < 128; d <<= 1) {
    int t = (tid >= d) ? buf[tid - d] : 0;
    __syncthreads();
    if (tid >= d) buf[tid] += t;
    __syncthreads();
  }
  boff[tid] = buf[tid] - v;   // exclusive
}

__global__ __launch_bounds__(256) void offsets_k(const int* __restrict__ deg,
                                                 const int* __restrict__ boff,
                                                 int* __restrict__ offsets) {
  __shared__ int buf[256];
  int tid = threadIdx.x;
  int i = blockIdx.x * 256 + tid;
  int v = deg[i];
  buf[tid] = v;
  __syncthreads();
  for (int d = 1; d < 256; d <<= 1) {
    int t = (tid >= d) ? buf[tid - d] : 0;
    __syncthreads();
    if (tid >= d) buf[tid] += t;
    __syncthreads();
  }
  offsets[i] = boff[blockIdx.x] + buf[tid] - v;
  if (i == 0) offsets[NN] = EE;
}

__global__ void bucket_k(const int* __restrict__ src, const int* __restrict__ dst,
                         const int* __restrict__ offsets, int* __restrict__ cursor,
                         int* __restrict__ srcs) {
  int e = blockIdx.x * 256 + threadIdx.x;
  if (e < EE) {
    int d = dst[e];
    int pos = offsets[d] + atomicAdd(&cursor[d], 1);
    srcs[pos] = src[e];
  }
}

// ---------------------------------------------------------------------------
// all weight conversions fused into one kernel (fp32 -> bf16, some padded)
// ---------------------------------------------------------------------------
#define CW1  73728        // w1b  [384x192]
#define CW2  172032       // w2b  [256x384]
#define CWL1 303104       // wl1b [512x256]
#define CWR1 434176
#define CWL2 696320       // [512x512]
#define CWR2 958464
#define CWL3 1220608
#define CWR3 1482752

__global__ void conv_all(const float* __restrict__ w1, const float* __restrict__ w2,
                         const float* __restrict__ wl1, const float* __restrict__ wr1,
                         const float* __restrict__ wl2, const float* __restrict__ wr2,
                         const float* __restrict__ wl3, const float* __restrict__ wr3,
                         unsigned short* __restrict__ w1b, unsigned short* __restrict__ w2b,
                         unsigned short* __restrict__ wl1b, unsigned short* __restrict__ wr1b,
                         unsigned short* __restrict__ wl2b, unsigned short* __restrict__ wr2b,
                         unsigned short* __restrict__ wl3b, unsigned short* __restrict__ wr3b) {
  int idx = blockIdx.x * 256 + threadIdx.x;
  if (idx >= CWR3) return;
  if (idx < CW1) {
    int r = idx / 192, c = idx - r * 192;
    w1b[idx] = f2bf((r < DX_ && c < D0_) ? w1[r * D0_ + c] : 0.0f);
  } else if (idx < CW2) {
    int i = idx - CW1;
    int r = i / 384, c = i - r * 384;
    w2b[i] = f2bf((c < DX_) ? w2[r * DX_ + c] : 0.0f);
  } else if (idx < CWL1) { int i = idx - CW2;  wl1b[i] = f2bf(wl1[i]); }
  else if (idx < CWR1)   { int i = idx - CWL1; wr1b[i] = f2bf(wr1[i]); }
  else if (idx < CWL2)   { int i = idx - CWR1; wl2b[i] = f2bf(wl2[i]); }
  else if (idx < CWR2)   { int i = idx - CWL2; wr2b[i] = f2bf(wr2[i]); }
  else if (idx < CWL3)   { int i = idx - CWR2; wl3b[i] = f2bf(wl3[i]); }
  else                   { int i = idx - CWL3; wr3b[i] = f2bf(wr3[i]); }
}

// ---------------------------------------------------------------------------
// x0 bf16 = concat([nf, ncf, emb[ops]]) padded to 192 cols
// ---------------------------------------------------------------------------
__global__ void build_x0_bf16(const float* __restrict__ nf, const float* __restrict__ ncf,
                              const float* __restrict__ emb, const int* __restrict__ ops,
                              unsigned short* __restrict__ x0) {
  int idx = blockIdx.x * 256 + threadIdx.x;
  if (idx >= NN * 192) return;
  int n = idx / 192;
  int c = idx - n * 192;
  float v;
  if (c < NF_)            v = nf[n * NF_ + c];
  else if (c < NF_ + NC_) v = ncf[n * NC_ + (c - NF_)];
  else if (c < D0_)       v = emb[ops[n] * OD_ + (c - (NF_ + NC_))];
  else                    v = 0.0f;
  x0[idx] = f2bf(v);
}

// ---------------------------------------------------------------------------
// bf16 MFMA GEMM (NT), two-phase: acc = A1*B1^T + A2*B2^T
// 128x128 tile, 256 thr = 4 waves (2x2), each wave 64x64 via 4x4 mfma 16x16x32.
// mode 1: C=leaky(acc+bias), fused scalar (GLN) stats -> st0/st1[seg]
// mode 2: C=acc+bias, fused column (PairNorm) stats -> st0/st1[col]
// mode 3: no C write; out[seg] += sum_rows dot(acc+bias, wcp)
// swz=1: 1D grid 1024, XCD-aware decode keeping same-bm tiles on one XCD.
// ---------------------------------------------------------------------------
__device__ __forceinline__ void stage_tile_async(const unsigned short* __restrict__ G, int ld,
                                                 int base_row, int k0,
                                                 unsigned short* __restrict__ lds, int tid) {
#pragma unroll
  for (int i = 0; i < 2; ++i) {
    int c = tid + i * 256;        // 0..511
    int row = c & 127;
    int off = c >> 7;             // 0..3 (k chunk of 8 bf16)
    const unsigned short* src = G + (size_t)(base_row + row) * ld + k0 + off * 8;
    unsigned short* dst = lds + off * 1024 + row * 8;
    __builtin_amdgcn_global_load_lds((gas_ptr)(const void*)src, (las_ptr)(void*)dst,
                                     16, 0, 0);
  }
}

__global__ __launch_bounds__(256) void mfma_gemm2(
    const unsigned short* __restrict__ A1, int lda1,
    const unsigned short* __restrict__ B1, int ldb1, int K1,
    const unsigned short* __restrict__ A2, int lda2,
    const unsigned short* __restrict__ B2, int ldb2, int K2,
    const float* __restrict__ bias,
    float* __restrict__ C, int ldc, int Nreal, int mode, int swz,
    float* __restrict__ st0, float* __restrict__ st1,
    const float* __restrict__ wcp, float* __restrict__ outp)
{
  __shared__ unsigned short As[4096];
  __shared__ unsigned short Bs[4096];
  __shared__ float red[256];
  __shared__ float cs[128], css[128];
  int tid = threadIdx.x;
  int lane = tid & 63;
  int w = tid >> 6;
  int wm = (w & 1) * 64;
  int wn = (w >> 1) * 64;
  int bm, bn;
  if (swz) {
    int L = blockIdx.x;
    int xcd = L & 7;
    int s = L >> 3;
    bn = (s & 3) * 128;
    bm = ((s >> 2) * 8 + xcd) * 128;
  } else {
    bm = blockIdx.y * 128;
    bn = blockIdx.x * 128;
  }
  int quad = lane >> 4;      // 0..3
  int r16 = lane & 15;

  f4v acc[4][4] = {};

#pragma unroll 1
  for (int ph = 0; ph < 2; ++ph) {
    const unsigned short* A = ph ? A2 : A1;
    const unsigned short* B = ph ? B2 : B1;
    int lda = ph ? lda2 : lda1;
    int ldb = ph ? ldb2 : ldb1;
    int K = ph ? K2 : K1;
    for (int k0 = 0; k0 < K; k0 += 32) {
      stage_tile_async(A, lda, bm, k0, As, tid);
      stage_tile_async(B, ldb, bn, k0, Bs, tid);
      __syncthreads();
      s8v af[4], bfr[4];
#pragma unroll
      for (int mi = 0; mi < 4; ++mi)
        af[mi] = *(const s8v*)&As[quad * 1024 + (wm + mi * 16 + r16) * 8];
#pragma unroll
      for (int ni = 0; ni < 4; ++ni)
        bfr[ni] = *(const s8v*)&Bs[quad * 1024 + (wn + ni * 16 + r16) * 8];
#pragma unroll
      for (int mi = 0; mi < 4; ++mi)
#pragma unroll
        for (int ni = 0; ni < 4; ++ni)
          acc[mi][ni] = __builtin_amdgcn_mfma_f32_16x16x32_bf16(
              af[mi], bfr[ni], acc[mi][ni], 0, 0, 0);
      __syncthreads();
    }
  }

  int seg = bm >> 8;

  if (mode == 1) {
    // write leaky(acc+bias), accumulate scalar sum/ssq (cols < Nreal)
    float lsum = 0.0f, lssq = 0.0f;
#pragma unroll
    for (int mi = 0; mi < 4; ++mi) {
      int gm = bm + wm + mi * 16 + quad * 4;
#pragma unroll
      for (int ni = 0; ni < 4; ++ni) {
        int gn = bn + wn + ni * 16 + r16;
        if (gn < Nreal) {
          float bv = bias[gn];
#pragma unroll
          for (int r = 0; r < 4; ++r) {
            float v = acc[mi][ni][r] + bv;
            v = (v >= 0.0f) ? v : 0.01f * v;
            C[(size_t)(gm + r) * ldc + gn] = v;
            lsum += v;
            lssq += v * v;
          }
        }
      }
    }
    red[tid] = lsum;
    __syncthreads();
    for (int off = 128; off > 0; off >>= 1) {
      if (tid < off) red[tid] += red[tid + off];
      __syncthreads();
    }
    if (tid == 0) atomicAdd(&st0[seg], red[0]);
    __syncthreads();
    red[tid] = lssq;
    __syncthreads();
    for (int off = 128; off > 0; off >>= 1) {
      if (tid < off) red[tid] += red[tid + off];
      __syncthreads();
    }
    if (tid == 0) atomicAdd(&st1[seg], red[0]);
  } else if (mode == 2) {
    // write acc+bias, accumulate per-column sum/ssq
    if (tid < 128) { cs[tid] = 0.0f; css[tid] = 0.0f; }
    __syncthreads();
#pragma unroll
    for (int ni = 0; ni < 4; ++ni) {
      int col = wn + ni * 16 + r16;       // 0..127
      int gn = bn + col;
      float bv = bias[gn];
      float psum = 0.0f, pssq = 0.0f;
#pragma unroll
      for (int mi = 0; mi < 4; ++mi) {
        int gm = bm + wm + mi * 16 + quad * 4;
#pragma unroll
        for (int r = 0; r < 4; ++r) {
          float v = acc[mi][ni][r] + bv;
          C[(size_t)(gm + r) * ldc + gn] = v;
          psum += v;
          pssq += v * v;
        }
      }
      atomicAdd(&cs[col], psum);
      atomicAdd(&css[col], pssq);
    }
    __syncthreads();
    if (tid < 128) {
      atomicAdd(&st0[bn + tid], cs[tid]);
      atomicAdd(&st1[bn + tid], css[tid]);
    }
  } else {
    // mode 3: pooled head — out[seg] += sum_rows dot(acc+bias, wc)
    float part = 0.0f;
#pragma unroll
    for (int ni = 0; ni < 4; ++ni) {
      int gn = bn + wn + ni * 16 + r16;
      float bv = bias[gn];
      float wv = wcp[gn];
      float colsum = 0.0f;
#pragma unroll
      for (int mi = 0; mi < 4; ++mi)
#pragma unroll
        for (int r = 0; r < 4; ++r)
          colsum += acc[mi][ni][r] + bv;
      part += colsum * wv;
    }
    red[tid] = part;
    __syncthreads();
    for (int off = 128; off > 0; off >>= 1) {
      if (tid < off) red[tid] += red[tid + off];
      __syncthreads();
    }
    if (tid == 0) atomicAdd(&outp[seg], red[0]);
  }
}

// ---------------------------------------------------------------------------
// GLN apply (finalize folded in): x fp32 -> bf16 padded
// ---------------------------------------------------------------------------
__global__ __launch_bounds__(256) void gln_apply_bf16(
    const float* __restrict__ x, int ld, int D, int Dp,
    const float* __restrict__ seg_sum, const float* __restrict__ seg_ssq,
    const float* __restrict__ g, const float* __restrict__ be,
    unsigned short* __restrict__ out) {
  int r = blockIdx.x;
  int s = r >> 8;
  float cnt = 256.0f * (float)D;
  float m = seg_sum[s] / cnt;
  float var = seg_ssq[s] / cnt - m * m;
  float inv = rsqrtf(var + 1e-5f);
  const float* row = x + (size_t)r * ld;
  unsigned short* orow = out + (size_t)r * Dp;
  for (int c = threadIdx.x; c < Dp; c += 256) {
    float v = (c < D) ? ((row[c] - m) * inv * g[c] + be[c]) : 0.0f;
    orow[c] = f2bf(v);
  }
}

// ---------------------------------------------------------------------------
// neighbor-mean aggregation: uint2 (4 bf16) per lane, multi-node blocks
// blockDim 256; D4 = D/4 lanes per node; npb = 256/D4 nodes per block
// ---------------------------------------------------------------------------
__global__ __launch_bounds__(256) void aggregate4(const unsigned short* __restrict__ x,
                                                  int D4log,
                                                  unsigned short* __restrict__ agg,
                                                  const int* __restrict__ offsets,
                                                  const int* __restrict__ srcs,
                                                  const float* __restrict__ inv_deg) {
  int tid = threadIdx.x;
  int D4 = 1 << D4log;
  int npb = 256 >> D4log;
  int n = blockIdx.x * npb + (tid >> D4log);
  int f4 = tid & (D4 - 1);
  int start = offsets[n], end = offsets[n + 1];
  float wgt = inv_deg[n];
  const uint2* xb = (const uint2*)x;
  float a0 = 0.0f, a1 = 0.0f, a2 = 0.0f, a3 = 0.0f;
  for (int e = start; e < end; ++e) {
    uint2 v = xb[((size_t)srcs[e] << D4log) + f4];
    a0 += bf2f((unsigned short)(v.x & 0xffffu));
    a1 += bf2f((unsigned short)(v.x >> 16));
    a2 += bf2f((unsigned short)(v.y & 0xffffu));
    a3 += bf2f((unsigned short)(v.y >> 16));
  }
  uint2 o;
  o.x = ((unsigned)f2bf(a1 * wgt) << 16) | (unsigned)f2bf(a0 * wgt);
  o.y = ((unsigned)f2bf(a3 * wgt) << 16) | (unsigned)f2bf(a2 * wgt);
  ((uint2*)agg)[((size_t)n << D4log) + f4] = o;
}

// ---------------------------------------------------------------------------
// PairNorm finalize + vectorized apply (float4 in, uint2 out, +ReLU)
// ---------------------------------------------------------------------------
__global__ __launch_bounds__(512) void pn_finalize(const float* __restrict__ colsum,
                                                   const float* __restrict__ colssq,
                                                   float* __restrict__ mu,
                                                   float* __restrict__ invd) {
  int f = threadIdx.x;
  float m = colsum[f] / (float)NN;
  mu[f] = m;
  float t = colssq[f] / (float)NN - m * m;
  __shared__ float buf[512];
  buf[f] = t;
  __syncthreads();
  for (int off = 256; off > 0; off >>= 1) {
    if (f < off) buf[f] += buf[f + off];
    __syncthreads();
  }
  if (f == 0) invd[0] = 1.0f / (1e-5f + sqrtf(fmaxf(buf[0], 0.0f)));
}

__global__ __launch_bounds__(128) void pn_apply_v(const float* __restrict__ y,
                                                  const float* __restrict__ mu,
                                                  const float* __restrict__ invd,
                                                  unsigned short* __restrict__ xb) {
  int r = blockIdx.x;
  int f4 = threadIdx.x;             // 0..127
  float id = invd[0];
  float4 v = ((const float4*)(y + (size_t)r * GH_))[f4];
  float4 m = ((const float4*)mu)[f4];
  float v0 = fmaxf((v.x - m.x) * id, 0.0f);
  float v1 = fmaxf((v.y - m.y) * id, 0.0f);
  float v2 = fmaxf((v.z - m.z) * id, 0.0f);
  float v3 = fmaxf((v.w - m.w) * id, 0.0f);
  uint2 o;
  o.x = ((unsigned)f2bf(v1) << 16) | (unsigned)f2bf(v0);
  o.y = ((unsigned)f2bf(v3) << 16) | (unsigned)f2bf(v2);
  ((uint2*)(xb + (size_t)r * GH_))[f4] = o;
}

__global__ void init_out(float* __restrict__ out, const float* __restrict__ bc) {
  int s = threadIdx.x;
  if (s < SS) out[s] = bc[0];
}

// ---------------------------------------------------------------------------
extern "C" void kernel_launch(void* const* d_in, const int* in_sizes, int n_in,
                              void* d_out, int out_size, void* d_ws, size_t ws_size,
                              hipStream_t stream) {
  const float* node_features = (const float*)d_in[0];
  const float* node_config   = (const float*)d_in[1];
  const float* emb_table     = (const float*)d_in[2];
  const float* w1  = (const float*)d_in[3];
  const float* b1  = (const float*)d_in[4];
  const float* g1  = (const float*)d_in[5];
  const float* be1 = (const float*)d_in[6];
  const float* w2  = (const float*)d_in[7];
  const float* b2  = (const float*)d_in[8];
  const float* g2  = (const float*)d_in[9];
  const float* be2 = (const float*)d_in[10];
  const float* wl1 = (const float*)d_in[11];
  const float* bl1 = (const float*)d_in[12];
  const float* wr1 = (const float*)d_in[13];
  const float* wl2 = (const float*)d_in[14];
  const float* bl2 = (const float*)d_in[15];
  const float* wr2 = (const float*)d_in[16];
  const float* wl3 = (const float*)d_in[17];
  const float* bl3 = (const float*)d_in[18];
  const float* wr3 = (const float*)d_in[19];
  const float* wc  = (const float*)d_in[20];
  const float* bc  = (const float*)d_in[21];
  const int* node_ops = (const int*)d_in[22];
  const int* edges    = (const int*)d_in[23];
  float* out = (float*)d_out;

  char* ws = (char*)d_ws;
  size_t off = 0;
  auto alloc = [&](size_t bytes) -> void* {
    void* p = ws + off;
    off += (bytes + 255) & ~(size_t)255;
    return p;
  };

  int*   deg_i   = (int*)alloc(NN * 4);
  int*   cursor  = (int*)alloc(NN * 4);
  int*   offsets = (int*)alloc((NN + 1) * 4);
  int*   srcs    = (int*)alloc(EE * 4);
  int*   bsum    = (int*)alloc(SS * 4);
  int*   boff    = (int*)alloc(SS * 4);
  float* inv_deg = (float*)alloc(NN * 4);
  float* seg_sum = (float*)alloc(SS * 4);   // seg_ssq follows contiguously
  float* seg_ssq = (float*)alloc(SS * 4);
  float* colsum  = (float*)alloc(512 * 4);  // colssq follows (4KB memset)
  float* colssq  = (float*)alloc(512 * 4);
  float* mu      = (float*)alloc(512 * 4);
  float* invd    = (float*)alloc(256);
  // bf16 weights (padded)
  unsigned short* w1b  = (unsigned short*)alloc((size_t)384 * 192 * 2);
  unsigned short* w2b  = (unsigned short*)alloc((size_t)256 * 384 * 2);
  unsigned short* wl1b = (unsigned short*)alloc((size_t)512 * 256 * 2);
  unsigned short* wr1b = (unsigned short*)alloc((size_t)512 * 256 * 2);
  unsigned short* wl2b = (unsigned short*)alloc((size_t)512 * 512 * 2);
  unsigned short* wr2b = (unsigned short*)alloc((size_t)512 * 512 * 2);
  unsigned short* wl3b = (unsigned short*)alloc((size_t)512 * 512 * 2);
  unsigned short* wr3b = (unsigned short*)alloc((size_t)512 * 512 * 2);
  // fp32 GEMM output slab + three rotating bf16 slabs
  float*          Y    = (float*)alloc((size_t)NN * 512 * 4);          // 67 MB
  unsigned short* BF1  = (unsigned short*)alloc((size_t)NN * 512 * 2); // 33.5 MB
  unsigned short* BF2  = (unsigned short*)alloc((size_t)NN * 512 * 2);
  unsigned short* BF3  = (unsigned short*)alloc((size_t)NN * 512 * 2);

  const int* esrc = edges;
  const int* edst = edges + EE;

  // ---- CSR build ----
  hipMemsetAsync(deg_i, 0, NN * 4, stream);
  hipMemsetAsync(cursor, 0, NN * 4, stream);
  deg_count<<<EE / 256, 256, 0, stream>>>(edst, deg_i);
  blk_sum_k<<<NN / 256, 256, 0, stream>>>(deg_i, bsum);
  blk_scan_k<<<1, 128, 0, stream>>>(bsum, boff);
  offsets_k<<<NN / 256, 256, 0, stream>>>(deg_i, boff, offsets);
  inv_deg_k<<<NN / 256, 256, 0, stream>>>(deg_i, inv_deg);
  bucket_k<<<EE / 256, 256, 0, stream>>>(esrc, edst, offsets, cursor, srcs);

  // ---- weight conversion (single kernel) ----
  conv_all<<<(CWR3 + 255) / 256, 256, 0, stream>>>(w1, w2, wl1, wr1, wl2, wr2, wl3, wr3,
                                                   w1b, w2b, wl1b, wr1b, wl2b, wr2b,
                                                   wl3b, wr3b);

  // ---- init output (bc) early so SAGE3 can accumulate into it ----
  init_out<<<1, SS, 0, stream>>>(out, bc);

  // ---- feature MLP ----
  build_x0_bf16<<<(NN * 192 + 255) / 256, 256, 0, stream>>>(node_features, node_config,
                                                            emb_table, node_ops, BF1);
  hipMemsetAsync(seg_sum, 0, 1024, stream);   // seg_sum + seg_ssq
  {  // Y = leaky(x0 @ w1^T + b1), fused GLN scalar stats
    dim3 g(384 / 128, NN / 128);
    mfma_gemm2<<<g, 256, 0, stream>>>(BF1, 192, w1b, 192, 192,
                                      nullptr, 0, nullptr, 0, 0,
                                      b1, Y, 384, DX_, 1, 0,
                                      seg_sum, seg_ssq, nullptr, nullptr);
  }
  gln_apply_bf16<<<NN, 256, 0, stream>>>(Y, 384, DX_, 384, seg_sum, seg_ssq, g1, be1, BF2);

  hipMemsetAsync(seg_sum, 0, 1024, stream);
  {  // Y = leaky(h1 @ w2^T + b2), fused GLN scalar stats
    dim3 g(256 / 128, NN / 128);
    mfma_gemm2<<<g, 256, 0, stream>>>(BF2, 384, w2b, 384, 384,
                                      nullptr, 0, nullptr, 0, 0,
                                      b2, Y, 256, GIN_, 1, 0,
                                      seg_sum, seg_ssq, nullptr, nullptr);
  }
  gln_apply_bf16<<<NN, 256, 0, stream>>>(Y, 256, GIN_, 256, seg_sum, seg_ssq, g2, be2, BF3);

  // ---- SAGE layer 1: agg(BF1) <- h2(BF3); Y = agg@wl1 + h2@wr1 (+col stats) ----
  aggregate4<<<NN / 4, 256, 0, stream>>>(BF3, 6, BF1, offsets, srcs, inv_deg);
  hipMemsetAsync(colsum, 0, 4096, stream);
  mfma_gemm2<<<1024, 256, 0, stream>>>(BF1, 256, wl1b, 256, 256,
                                       BF3, 256, wr1b, 256, 256,
                                       bl1, Y, 512, GH_, 2, 1,
                                       colsum, colssq, nullptr, nullptr);
  pn_finalize<<<1, 512, 0, stream>>>(colsum, colssq, mu, invd);
  pn_apply_v<<<NN, 128, 0, stream>>>(Y, mu, invd, BF2);   // x1 -> BF2

  // ---- SAGE layer 2: agg(BF1) <- x1(BF2) ----
  aggregate4<<<NN / 2, 256, 0, stream>>>(BF2, 7, BF1, offsets, srcs, inv_deg);
  hipMemsetAsync(colsum, 0, 4096, stream);
  mfma_gemm2<<<1024, 256, 0, stream>>>(BF1, 512, wl2b, 512, 512,
                                       BF2, 512, wr2b, 512, 512,
                                       bl2, Y, 512, GH_, 2, 1,
                                       colsum, colssq, nullptr, nullptr);
  pn_finalize<<<1, 512, 0, stream>>>(colsum, colssq, mu, invd);
  pn_apply_v<<<NN, 128, 0, stream>>>(Y, mu, invd, BF3);   // x2 -> BF3

  // ---- SAGE layer 3 + pooled head fused (no Y write) ----
  aggregate4<<<NN / 2, 256, 0, stream>>>(BF3, 7, BF1, offsets, srcs, inv_deg);
  mfma_gemm2<<<1024, 256, 0, stream>>>(BF1, 512, wl3b, 512, 512,
                                       BF3, 512, wr3b, 512, 512,
                                       bl3, nullptr, 512, GH_, 3, 1,
                                       nullptr, nullptr, wc, out);
}